// Round 2
// baseline (66.248 us; speedup 1.0000x reference)
//
#include <hip/hip_runtime.h>
#include <math.h>

// GaussianImage Cholesky splat render: 1024 gaussians -> (3, 256, 256).
// R2: two-kernel pipeline.
//   K1 (1 block x 1024 thr): project each gaussian ONCE, compute conservative
//      support bbox (alpha>=1/255 <=> sigma<=ln(255*op)), scatter gaussian
//      index into per-16x16-tile lists in d_ws via global atomics. Zeroes the
//      256 tile counters itself (syncthreads before atomics) since d_ws is
//      re-poisoned to 0xAA before every timed launch.
//   K2 (256 blocks x 256 thr, 1 px/thread): load this tile's ~15-entry list,
//      gather params into LDS, shade. Removes the 256x redundant projection
//      of R1 (262K projections -> 1024).

constexpr int HH = 256;
constexpr int WW = 256;
constexpr int TILE = 16;
constexpr int NT = 16;              // tiles per side
constexpr int MAXG = 1024;          // per-tile list capacity == N (no overflow)
constexpr float ALPHA_T = 1.0f / 255.0f;

__global__ __launch_bounds__(1024) void k1_project_scatter(
    const float* __restrict__ xyz,    // (N,2)
    const float* __restrict__ chol,   // (N,3)
    const float* __restrict__ feat,   // (N,3)
    const float* __restrict__ opac,   // (N,1)
    float4* __restrict__ P0,          // cx, cy, conic_a, conic_b
    float4* __restrict__ P1,          // conic_c, op, fr, fg
    float*  __restrict__ Pb,          // fb
    int* __restrict__ counters,       // [256]
    int* __restrict__ lists,          // [256][MAXG]
    int N)
{
    const int tid = threadIdx.x;
    if (tid < NT * NT) counters[tid] = 0;
    __syncthreads();

    for (int i = tid; i < N; i += 1024) {
        float mx = tanhf(xyz[2 * i]);
        float my = tanhf(xyz[2 * i + 1]);
        float cx = 0.5f * (float)WW * (mx + 1.0f);
        float cy = 0.5f * (float)HH * (my + 1.0f);
        float l1 = chol[3 * i]     + 0.5f;
        float l2 = chol[3 * i + 1];
        float l3 = chol[3 * i + 2] + 0.5f;
        float a = l1 * l1;
        float b = l1 * l2;
        float c = l2 * l2 + l3 * l3;
        float det = a * c - b * b;
        float ca = c / det;
        float cb = -b / det;
        float cc = a / det;
        float op = opac[i];

        P0[i] = make_float4(cx, cy, ca, cb);
        P1[i] = make_float4(cc, op, feat[3 * i], feat[3 * i + 1]);
        Pb[i] = feat[3 * i + 2];

        // support ellipse {0.5 d^T Sigma^-1 d <= T}, T = ln(255*op):
        // |dx|max = sqrt(2T)*l1, |dy|max = sqrt(2T)*sqrt(l2^2+l3^2).
        float T   = __logf(255.0f * op);
        float s2T = sqrtf(2.0f * T);
        float rx  = s2T * l1 + 0.05f;          // fp-safety margin
        float ry  = s2T * sqrtf(c) + 0.05f;

        // NaN-safe (NaN fails ==): culled gaussians (T<0 / bad det) skipped,
        // consistent with ref where w=0 there.
        bool ok = (cx == cx) && (cy == cy) && (rx == rx) && (ry == ry);
        if (!ok) continue;

        // tile t covers pixel centers [16t+0.5, 16t+15.5]
        int tx0 = max(0,      (int)ceilf ((cx - rx - 15.5f) * (1.0f / 16.0f)));
        int tx1 = min(NT - 1, (int)floorf((cx + rx - 0.5f)  * (1.0f / 16.0f)));
        int ty0 = max(0,      (int)ceilf ((cy - ry - 15.5f) * (1.0f / 16.0f)));
        int ty1 = min(NT - 1, (int)floorf((cy + ry - 0.5f)  * (1.0f / 16.0f)));
        for (int ty = ty0; ty <= ty1; ++ty)
            for (int tx = tx0; tx <= tx1; ++tx) {
                int t = ty * NT + tx;
                int slot = atomicAdd(&counters[t], 1);   // device-scope
                lists[t * MAXG + slot] = i;
            }
    }
}

__global__ __launch_bounds__(256) void k2_render(
    const float4* __restrict__ P0,
    const float4* __restrict__ P1,
    const float*  __restrict__ Pb,
    const int* __restrict__ counters,
    const int* __restrict__ lists,
    float* __restrict__ out)          // (3,H,W) flat
{
    __shared__ float4 sA[MAXG];
    __shared__ float4 sB[MAXG];
    __shared__ float  sC[MAXG];

    const int tile = blockIdx.x;
    const int tid = threadIdx.x;
    const int cnt = counters[tile];

    for (int j = tid; j < cnt; j += 256) {
        int idx = lists[tile * MAXG + j];
        sA[j] = P0[idx];
        sB[j] = P1[idx];
        sC[j] = Pb[idx];
    }
    __syncthreads();

    const int tx = tile & (NT - 1);
    const int ty = tile >> 4;
    const int x = tx * TILE + (tid & 15);
    const int y = ty * TILE + (tid >> 4);
    const float px = (float)x + 0.5f;
    const float py = (float)y + 0.5f;

    float accr = 0.0f, accg = 0.0f, accb = 0.0f;
    for (int j = 0; j < cnt; ++j) {
        float4 A = sA[j];            // uniform index -> LDS broadcast
        float4 B = sB[j];
        float fb = sC[j];
        float dx = A.x - px;
        float dy = A.y - py;
        // reference association: 0.5*(ca*dx*dx + cc*dy*dy) + cb*dx*dy
        float sigma = 0.5f * (A.z * dx * dx + B.x * dy * dy) + A.w * dx * dy;
        float alpha = fminf(0.999f, B.y * __expf(-sigma));
        float w = (sigma >= 0.0f && alpha >= ALPHA_T) ? alpha : 0.0f;
        accr = fmaf(w, B.z, accr);
        accg = fmaf(w, B.w, accg);
        accb = fmaf(w, fb, accb);
    }

    const int p = y * WW + x;
    out[p]               = fminf(fmaxf(accr, 0.0f), 1.0f);
    out[HH * WW + p]     = fminf(fmaxf(accg, 0.0f), 1.0f);
    out[2 * HH * WW + p] = fminf(fmaxf(accb, 0.0f), 1.0f);
}

extern "C" void kernel_launch(void* const* d_in, const int* in_sizes, int n_in,
                              void* d_out, int out_size, void* d_ws, size_t ws_size,
                              hipStream_t stream) {
    const float* xyz  = (const float*)d_in[0];
    const float* chol = (const float*)d_in[1];
    const float* feat = (const float*)d_in[2];
    const float* opac = (const float*)d_in[3];
    float* out = (float*)d_out;
    const int N = in_sizes[0] / 2;

    // d_ws layout (all offsets 16B-aligned):
    //   [0, 1KB)              int counters[256]
    //   [1KB, 1KB+1MB)        int lists[256][1024]
    //   then P0[1024] float4, P1[1024] float4, Pb[1024] float
    char* ws = (char*)d_ws;
    int*    counters = (int*)ws;
    int*    lists    = (int*)(ws + 1024);
    float4* P0       = (float4*)(ws + 1024 + 256 * MAXG * 4);
    float4* P1       = P0 + MAXG;
    float*  Pb       = (float*)(P1 + MAXG);

    k1_project_scatter<<<dim3(1), dim3(1024), 0, stream>>>(
        xyz, chol, feat, opac, P0, P1, Pb, counters, lists, N);
    k2_render<<<dim3(256), dim3(256), 0, stream>>>(
        P0, P1, Pb, counters, lists, out);
}

// Round 3
// 62.121 us; speedup vs baseline: 1.0664x; 1.0664x over previous
//
#include <hip/hip_runtime.h>
#include <math.h>

// GaussianImage Cholesky splat render: 1024 gaussians -> (3, 256, 256).
// R3: single kernel (R2 showed marginal launch ~2us > any split savings;
// dur_us is dominated by the harness's fixed 256MiB ws poison fill @39.5us).
// 1 block per 16x16 tile (256 blocks == 256 CUs, 1 px/thread). Each block
// re-projects all N gaussians (4/thread) with FAST intrinsics (the R1->R3
// change): tanh via 1-2*rcp(e^2x+1), /det via rcp -- ~40 cyc/gaussian vs
// ~200 for libm tanhf + 3 divides. Cull by conservative support bbox
// (alpha>=1/255 <=> sigma<=ln(255*op)), compact to LDS, shade.

constexpr int HH = 256;
constexpr int WW = 256;
constexpr int TILE = 16;
constexpr int MAXG = 1024;          // capacity == N, cannot overflow
constexpr float ALPHA_T = 1.0f / 255.0f;

__device__ __forceinline__ float fast_rcp(float x) {
    return __builtin_amdgcn_rcpf(x);
}
__device__ __forceinline__ float fast_tanh(float x) {
    // exact at saturation: e->inf => 1-0 = 1; e->0 => 1-2 = -1. No NaN.
    float e = __expf(2.0f * x);
    return 1.0f - 2.0f * fast_rcp(e + 1.0f);
}

__global__ __launch_bounds__(256) void gsplat_render(
    const float* __restrict__ xyz,    // (N,2)
    const float* __restrict__ chol,   // (N,3)
    const float* __restrict__ feat,   // (N,3)
    const float* __restrict__ opac,   // (N,1)
    float* __restrict__ out,          // (3,H,W) flat
    int N)
{
    __shared__ float4 cA[MAXG];   // cx, cy, conic_a, conic_b
    __shared__ float4 cB[MAXG];   // conic_c, op, fr, fg
    __shared__ float  cC[MAXG];   // fb
    __shared__ int    s_cnt;

    const int tid = threadIdx.x;
    if (tid == 0) s_cnt = 0;
    __syncthreads();

    const int tx = blockIdx.x & 15;
    const int ty = blockIdx.x >> 4;
    // pixel-center coordinate range covered by this tile
    const float x0c = (float)(tx * TILE) + 0.5f;
    const float x1c = (float)(tx * TILE + TILE - 1) + 0.5f;
    const float y0c = (float)(ty * TILE) + 0.5f;
    const float y1c = (float)(ty * TILE + TILE - 1) + 0.5f;

    // ---- project + cull + compact (fast-math projection) ----
    for (int i = tid; i < N; i += 256) {
        float mx = fast_tanh(xyz[2 * i]);
        float my = fast_tanh(xyz[2 * i + 1]);
        float cx = 0.5f * (float)WW * (mx + 1.0f);
        float cy = 0.5f * (float)HH * (my + 1.0f);
        float l1 = chol[3 * i]     + 0.5f;
        float l2 = chol[3 * i + 1];
        float l3 = chol[3 * i + 2] + 0.5f;
        float a = l1 * l1;
        float b = l1 * l2;
        float c = l2 * l2 + l3 * l3;
        float det  = a * c - b * b;          // == (l1*l3)^2 in exact arith
        float rdet = fast_rcp(det);
        float ca =  c * rdet;
        float cb = -b * rdet;
        float cc =  a * rdet;
        float op = opac[i];

        // support: op*exp(-sigma) >= 1/255  <=>  sigma <= T = ln(255*op)
        // ellipse {0.5 d^T Sigma^-1 d <= T}: |dx|max = sqrt(2T)*l1,
        // |dy|max = sqrt(2T*(l2^2+l3^2)). NaN radii/centers fail the
        // compares => culled, consistent with ref (w=0 there).
        float T   = __logf(255.0f * op);
        float s2T = sqrtf(2.0f * T);
        float rx  = s2T * l1 + 0.05f;           // fp-safety margin
        float ry  = s2T * sqrtf(c) + 0.05f;

        bool hit = (cx + rx >= x0c) && (cx - rx <= x1c) &&
                   (cy + ry >= y0c) && (cy - ry <= y1c);
        if (hit) {
            int slot = atomicAdd(&s_cnt, 1);
            if (slot < MAXG) {
                cA[slot] = make_float4(cx, cy, ca, cb);
                cB[slot] = make_float4(cc, op, feat[3 * i], feat[3 * i + 1]);
                cC[slot] = feat[3 * i + 2];
            }
        }
    }
    __syncthreads();
    const int cnt = min(s_cnt, MAXG);

    // ---- render this thread's pixel ----
    const int x = tx * TILE + (tid & 15);
    const int y = ty * TILE + (tid >> 4);
    const float px = (float)x + 0.5f;
    const float py = (float)y + 0.5f;

    float accr = 0.0f, accg = 0.0f, accb = 0.0f;
    for (int j = 0; j < cnt; ++j) {
        float4 A = cA[j];            // uniform index -> LDS broadcast
        float4 B = cB[j];
        float fb = cC[j];
        float dx = A.x - px;
        float dy = A.y - py;
        // reference association: 0.5*(ca*dx*dx + cc*dy*dy) + cb*dx*dy
        float sigma = 0.5f * (A.z * dx * dx + B.x * dy * dy) + A.w * dx * dy;
        float alpha = fminf(0.999f, B.y * __expf(-sigma));
        float w = (sigma >= 0.0f && alpha >= ALPHA_T) ? alpha : 0.0f;
        accr = fmaf(w, B.z, accr);
        accg = fmaf(w, B.w, accg);
        accb = fmaf(w, fb, accb);
    }

    const int p = y * WW + x;
    out[p]               = fminf(fmaxf(accr, 0.0f), 1.0f);
    out[HH * WW + p]     = fminf(fmaxf(accg, 0.0f), 1.0f);
    out[2 * HH * WW + p] = fminf(fmaxf(accb, 0.0f), 1.0f);
}

extern "C" void kernel_launch(void* const* d_in, const int* in_sizes, int n_in,
                              void* d_out, int out_size, void* d_ws, size_t ws_size,
                              hipStream_t stream) {
    const float* xyz  = (const float*)d_in[0];
    const float* chol = (const float*)d_in[1];
    const float* feat = (const float*)d_in[2];
    const float* opac = (const float*)d_in[3];
    float* out = (float*)d_out;
    const int N = in_sizes[0] / 2;

    gsplat_render<<<dim3(256), dim3(256), 0, stream>>>(xyz, chol, feat, opac, out, N);
}